// Round 9
// baseline (239.445 us; speedup 1.0000x reference)
//
#include <hip/hip_runtime.h>
#include <cstdint>

typedef unsigned short u16;
typedef __bf16 bf16x8 __attribute__((ext_vector_type(8)));
typedef float f32x4 __attribute__((ext_vector_type(4)));
typedef u16 u16x8 __attribute__((ext_vector_type(8)));

// Problem sizes: B=8, S=2048, I=256, H=256, M=1024
#define NX 4194304L
#define NW 65536L
#define NM 2097152L
#define WS_MEM (NW)
#define WS_KEY (NW + NM)

// ---- INSTRUMENTATION + A/B ROUND ----
// G1 x7, G2-A (2-buf depth-1, current) x3, G2-B (3-buf depth-2 counted vmcnt) x4.
// All three dispatches land >52us => full counters in top-5.
#define REPS_G1  7
#define REPS_G2A 3
#define REPS_G2B 4

__device__ __forceinline__ u16 f2bf_rne(float f) {
  union { float f; uint32_t u; } v; v.f = f;
  uint32_t r = v.u + 0x7fffu + ((v.u >> 16) & 1u);
  return (u16)(r >> 16);
}

__device__ __forceinline__ u16x8 cvt8(float4 a, float4 b) {
  u16x8 o;
  o[0]=f2bf_rne(a.x); o[1]=f2bf_rne(a.y); o[2]=f2bf_rne(a.z); o[3]=f2bf_rne(a.w);
  o[4]=f2bf_rne(b.x); o[5]=f2bf_rne(b.y); o[6]=f2bf_rne(b.z); o[7]=f2bf_rne(b.w);
  return o;
}

// ---- Kernel 0: fp32 -> bf16 pre-convert of W and mem ----
__global__ void convert_bf16_kernel(const float* __restrict__ mem,
                                    const float* __restrict__ W,
                                    u16* __restrict__ ws) {
  long e = ((long)blockIdx.x * blockDim.x + threadIdx.x) * 8;
  if (e >= NW + NM) return;
  const float* src; long l;
  if (e < NW) { src = W;   l = e; }
  else        { src = mem; l = e - NW; }
  float4 f0 = *(const float4*)(src + l);
  float4 f1 = *(const float4*)(src + l + 4);
  *(u16x8*)(ws + e) = cvt8(f0, f1);
}

// ================= GEMM1 (R7 config: BM=64, 512 blocks) + reps ==========
#define G1_BM 64
#define G1_BN 128
#define BK 32

template<int REPS>
__global__ __launch_bounds__(256, 2)
void gemm1_x(const float* __restrict__ x, const u16* __restrict__ Wb,
             float* __restrict__ key_f, u16* __restrict__ key_bf)
{
  const int K = 256, N = 256;
  __shared__ __align__(16) u16 sA[2][G1_BM * BK];
  __shared__ __align__(16) u16 sB[2][G1_BN * BK];
  const int tid  = threadIdx.x;
  const int wave = tid >> 6;
  const int lane = tid & 63;
  const int quad = lane >> 4;
  const int r    = lane & 15;
  const int wm   = wave >> 1;
  const int wn   = wave & 1;

  const int gx  = gridDim.x;
  const int nwg = gx * (int)gridDim.y;
  const int id  = (int)blockIdx.x + gx * (int)blockIdx.y;
  const int cpx = nwg >> 3;
  const int lid = (id & 7) * cpx + (id >> 3);
  const int bm  = (lid / gx) * G1_BM;
  const int bn  = (lid % gx) * G1_BN;

  const long ldr = (long)K * 2;

  const int o0 = wave * 1024 + lane * 16;
  auto stageB = [&](int buf, int kt) {
    #pragma unroll
    for (int rr = 0; rr < 2; rr++) {
      const int o    = rr * 4096 + o0;
      const int row  = o >> 6;
      const int colb = o & 63;
      const char* g = (const char*)Wb + (long)(bn + row) * ldr + (long)kt * 2 + colb;
      char* l = (char*)&sB[buf][0] + rr * 4096 + wave * 1024;
      __builtin_amdgcn_global_load_lds((const __attribute__((address_space(1))) void*)g,
                                       (__attribute__((address_space(3))) void*)l, 16, 0, 0);
    }
  };

  float4 xa[2];
  const int arow = tid >> 2;
  const int ac0  = (tid & 3) * 8;
  auto loadA = [&](int kt) {
    const float* g = x + (long)(bm + arow) * K + kt + ac0;
    xa[0] = *(const float4*)g;
    xa[1] = *(const float4*)(g + 4);
  };
  auto writeA = [&](int buf) {
    *(u16x8*)&sA[buf][arow * BK + ac0] = cvt8(xa[0], xa[1]);
  };

  for (int rep = 0; rep < REPS; ++rep) {
    f32x4 acc[2][4];
    #pragma unroll
    for (int i = 0; i < 2; i++)
      #pragma unroll
      for (int j = 0; j < 4; j++)
        acc[i][j] = f32x4{0.f, 0.f, 0.f, 0.f};

    loadA(0); writeA(0);
    stageB(0, 0);
    __syncthreads();

    const int NT = K / BK;
    for (int t = 0; t < NT; ++t) {
      const int cur = t & 1, nxt = cur ^ 1;
      const bool pf = (t + 1 < NT);
      if (pf) {
        loadA((t + 1) * BK);
        stageB(nxt, (t + 1) * BK);
      }
      bf16x8 af[2], bfr[4];
      #pragma unroll
      for (int i = 0; i < 2; i++)
        af[i] = *(const bf16x8*)&sA[cur][(wm * 32 + i * 16 + r) * BK + quad * 8];
      #pragma unroll
      for (int j = 0; j < 4; j++)
        bfr[j] = *(const bf16x8*)&sB[cur][(wn * 64 + j * 16 + r) * BK + quad * 8];
      #pragma unroll
      for (int i = 0; i < 2; i++)
        #pragma unroll
        for (int j = 0; j < 4; j++)
          acc[i][j] = __builtin_amdgcn_mfma_f32_16x16x32_bf16(af[i], bfr[j], acc[i][j], 0, 0, 0);
      if (pf) writeA(nxt);
      __syncthreads();
    }

    #pragma unroll
    for (int i = 0; i < 2; i++) {
      #pragma unroll
      for (int j = 0; j < 4; j++) {
        #pragma unroll
        for (int reg = 0; reg < 4; reg++) {
          const int row = bm + wm * 32 + i * 16 + quad * 4 + reg;
          const int col = bn + wn * 64 + j * 16 + r;
          float v = acc[i][j][reg];
          v = v > 0.f ? v : 0.f;
          const long idx = (long)row * N + col;
          key_f[idx]  = v;
          key_bf[idx] = f2bf_rne(v);
        }
      }
    }
  }
}

// ================= GEMM2 A/B: NBUF=2 (depth-1, drain) vs NBUF=3 (depth-2, vmcnt(4)) ===
#define BM 128
#define BN 128

template<int NBUF, int REPS>
__global__ __launch_bounds__(256, 3)
void gemm2_t(const u16* __restrict__ A, const u16* __restrict__ B,
             float* __restrict__ C,
             int M, int N, int K,
             long sA_batch, long sB_batch, long sC_batch)
{
  __shared__ __align__(16) u16 sA[NBUF][BM * BK];
  __shared__ __align__(16) u16 sB[NBUF][BN * BK];
  const int tid  = threadIdx.x;
  const int wave = tid >> 6;
  const int lane = tid & 63;
  const int quad = lane >> 4;
  const int r    = lane & 15;
  const int wm   = wave >> 1;
  const int wn   = wave & 1;

  const int gx  = gridDim.x, gy = gridDim.y;
  const int nwg = gx * gy * (int)gridDim.z;
  const int id  = (int)blockIdx.x + gx * ((int)blockIdx.y + gy * (int)blockIdx.z);
  const int cpx = nwg >> 3;
  const int lid = (id & 7) * cpx + (id >> 3);
  const int bx  = lid % gx;
  const int tq  = lid / gx;
  const int by  = tq % gy;
  const int bz  = tq / gy;

  const int bm    = by * BM;
  const int bn    = bx * BN;
  const int batch = bz;

  const char* Ab = (const char*)(A + (long)batch * sA_batch);
  const char* Bb = (const char*)(B + (long)batch * sB_batch);
  const long ldr = (long)K * 2;

  const int o0 = wave * 1024 + lane * 16;
  auto stage = [&](u16* dst, const char* src, int kt) {
    #pragma unroll
    for (int rr = 0; rr < 2; rr++) {
      const int o    = rr * 4096 + o0;
      const int row  = o >> 6;
      const int colb = o & 63;
      const char* g = src + (long)row * ldr + (long)kt * 2 + colb;
      char* l = (char*)dst + rr * 4096 + wave * 1024;
      __builtin_amdgcn_global_load_lds((const __attribute__((address_space(1))) void*)g,
                                       (__attribute__((address_space(3))) void*)l, 16, 0, 0);
    }
  };
  const char* Asrc = Ab + (long)bm * ldr;
  const char* Bsrc = Bb + (long)bn * ldr;

  const int NT = K / BK;
  for (int rep = 0; rep < REPS; ++rep) {
    f32x4 acc[4][4];
    #pragma unroll
    for (int i = 0; i < 4; i++)
      #pragma unroll
      for (int j = 0; j < 4; j++)
        acc[i][j] = f32x4{0.f, 0.f, 0.f, 0.f};

    if constexpr (NBUF == 2) {
      stage(&sA[0][0], Asrc, 0);
      stage(&sB[0][0], Bsrc, 0);
      __syncthreads();
    } else {
      // depth-2 prologue: tiles 0 and 1 in flight; wait only tile 0 (vmcnt(4))
      stage(&sA[0][0], Asrc, 0);
      stage(&sB[0][0], Bsrc, 0);
      stage(&sA[1][0], Asrc, BK);
      stage(&sB[1][0], Bsrc, BK);
      asm volatile("s_waitcnt vmcnt(4)" ::: "memory");
      __builtin_amdgcn_s_barrier();
      __builtin_amdgcn_sched_barrier(0);
    }

    for (int t = 0; t < NT; ++t) {
      if constexpr (NBUF == 2) {
        const int cur = t & 1, nxt = cur ^ 1;
        if (t + 1 < NT) {
          stage(&sA[nxt][0], Asrc, (t + 1) * BK);
          stage(&sB[nxt][0], Bsrc, (t + 1) * BK);
        }
        bf16x8 af[4], bfr[4];
        #pragma unroll
        for (int i = 0; i < 4; i++)
          af[i] = *(const bf16x8*)&sA[cur][(wm * 64 + i * 16 + r) * BK + quad * 8];
        #pragma unroll
        for (int j = 0; j < 4; j++)
          bfr[j] = *(const bf16x8*)&sB[cur][(wn * 64 + j * 16 + r) * BK + quad * 8];
        #pragma unroll
        for (int i = 0; i < 4; i++)
          #pragma unroll
          for (int j = 0; j < 4; j++)
            acc[i][j] = __builtin_amdgcn_mfma_f32_16x16x32_bf16(af[i], bfr[j], acc[i][j], 0, 0, 0);
        __syncthreads();
      } else {
        const int cur = t % 3;
        if (t + 2 < NT) {
          const int nb = (t + 2) % 3;
          stage(&sA[nb][0], Asrc, (t + 2) * BK);
          stage(&sB[nb][0], Bsrc, (t + 2) * BK);
        }
        bf16x8 af[4], bfr[4];
        #pragma unroll
        for (int i = 0; i < 4; i++)
          af[i] = *(const bf16x8*)&sA[cur][(wm * 64 + i * 16 + r) * BK + quad * 8];
        #pragma unroll
        for (int j = 0; j < 4; j++)
          bfr[j] = *(const bf16x8*)&sB[cur][(wn * 64 + j * 16 + r) * BK + quad * 8];
        #pragma unroll
        for (int i = 0; i < 4; i++)
          #pragma unroll
          for (int j = 0; j < 4; j++)
            acc[i][j] = __builtin_amdgcn_mfma_f32_16x16x32_bf16(af[i], bfr[j], acc[i][j], 0, 0, 0);
        if (t + 1 < NT) {
          // wait tile t+1 complete BEFORE barrier; leave tile t+2's 4 loads in flight
          if (t + 2 < NT) asm volatile("s_waitcnt vmcnt(4)" ::: "memory");
          else            asm volatile("s_waitcnt vmcnt(0)" ::: "memory");
          __builtin_amdgcn_s_barrier();
          __builtin_amdgcn_sched_barrier(0);
        }
      }
    }

    float* Co = C + (long)batch * sC_batch;
    #pragma unroll
    for (int i = 0; i < 4; i++) {
      #pragma unroll
      for (int j = 0; j < 4; j++) {
        #pragma unroll
        for (int reg = 0; reg < 4; reg++) {
          const int row = bm + wm * 64 + i * 16 + quad * 4 + reg;
          const int col = bn + wn * 64 + j * 16 + r;
          Co[(long)row * N + col] = acc[i][j][reg];
        }
      }
    }
    if constexpr (NBUF == 3) __syncthreads();  // rep isolation (prologue rewrites bufs 0,1)
  }
}

extern "C" void kernel_launch(void* const* d_in, const int* in_sizes, int n_in,
                              void* d_out, int out_size, void* d_ws, size_t ws_size,
                              hipStream_t stream) {
  const float* x   = (const float*)d_in[0];
  const float* mem = (const float*)d_in[1];
  const float* W   = (const float*)d_in[2];
  float* out   = (float*)d_out;
  float* key_f = out;
  float* val_f = out + NX;
  u16* ws     = (u16*)d_ws;
  u16* W_bf   = ws;
  u16* mem_bf = ws + WS_MEM;
  u16* key_bf = ws + WS_KEY;

  convert_bf16_kernel<<<(int)((NW + NM) / 8 / 256), 256, 0, stream>>>(mem, W, ws);

  dim3 g1(256 / G1_BN, 16384 / G1_BM, 1);
  gemm1_x<REPS_G1><<<g1, 256, 0, stream>>>(x, W_bf, key_f, key_bf);

  dim3 g2(1024 / BN, 2048 / BM, 8);
  // variant A: current 2-buffer depth-1 (baseline counters)
  gemm2_t<2, REPS_G2A><<<g2, 256, 0, stream>>>(key_bf, mem_bf, val_f,
                                               2048, 1024, 256,
                                               (long)2048 * 256, (long)1024 * 256,
                                               (long)2048 * 1024);
  // variant B: 3-buffer depth-2 counted-vmcnt pipeline (T4)
  gemm2_t<3, REPS_G2B><<<g2, 256, 0, stream>>>(key_bf, mem_bf, val_f,
                                               2048, 1024, 256,
                                               (long)2048 * 256, (long)1024 * 256,
                                               (long)2048 * 1024);
}

// Round 12
// 126.454 us; speedup vs baseline: 1.8935x; 1.8935x over previous
//
#include <hip/hip_runtime.h>
#include <cstdint>

typedef unsigned short u16;
typedef __bf16 bf16x8 __attribute__((ext_vector_type(8)));
typedef float f32x4 __attribute__((ext_vector_type(4)));
typedef u16 u16x8 __attribute__((ext_vector_type(8)));

// Problem sizes: B=8, S=2048, I=256, H=256, M=1024
#define NX 4194304L
#define NW 65536L
#define NM 2097152L
#define WS_MEM (NW)
#define WS_KEY (NW + NM)

__device__ __forceinline__ u16 f2bf_rne(float f) {
  union { float f; uint32_t u; } v; v.f = f;
  uint32_t r = v.u + 0x7fffu + ((v.u >> 16) & 1u);
  return (u16)(r >> 16);
}

__device__ __forceinline__ u16x8 cvt8(float4 a, float4 b) {
  u16x8 o;
  o[0]=f2bf_rne(a.x); o[1]=f2bf_rne(a.y); o[2]=f2bf_rne(a.z); o[3]=f2bf_rne(a.w);
  o[4]=f2bf_rne(b.x); o[5]=f2bf_rne(b.y); o[6]=f2bf_rne(b.z); o[7]=f2bf_rne(b.w);
  return o;
}

// ---- Kernel 0: fp32 -> bf16 pre-convert of W and mem ----
__global__ void convert_bf16_kernel(const float* __restrict__ mem,
                                    const float* __restrict__ W,
                                    u16* __restrict__ ws) {
  long e = ((long)blockIdx.x * blockDim.x + threadIdx.x) * 8;
  if (e >= NW + NM) return;
  const float* src; long l;
  if (e < NW) { src = W;   l = e; }
  else        { src = mem; l = e - NW; }
  float4 f0 = *(const float4*)(src + l);
  float4 f1 = *(const float4*)(src + l + 4);
  *(u16x8*)(ws + e) = cvt8(f0, f1);
}

// ================= GEMM1 (R7 config: BM=64, 512 blocks, verified) ==========
#define G1_BM 64
#define G1_BN 128
#define BK 32

__global__ __launch_bounds__(256, 2)
void gemm1_x(const float* __restrict__ x, const u16* __restrict__ Wb,
             float* __restrict__ key_f, u16* __restrict__ key_bf)
{
  const int K = 256, N = 256;
  __shared__ __align__(16) u16 sA[2][G1_BM * BK];
  __shared__ __align__(16) u16 sB[2][G1_BN * BK];
  const int tid  = threadIdx.x;
  const int wave = tid >> 6;
  const int lane = tid & 63;
  const int quad = lane >> 4;
  const int r    = lane & 15;
  const int wm   = wave >> 1;
  const int wn   = wave & 1;

  const int gx  = gridDim.x;
  const int nwg = gx * (int)gridDim.y;
  const int id  = (int)blockIdx.x + gx * (int)blockIdx.y;
  const int cpx = nwg >> 3;
  const int lid = (id & 7) * cpx + (id >> 3);
  const int bm  = (lid / gx) * G1_BM;
  const int bn  = (lid % gx) * G1_BN;

  const long ldr = (long)K * 2;

  const int o0 = wave * 1024 + lane * 16;
  auto stageB = [&](int buf, int kt) {
    #pragma unroll
    for (int rr = 0; rr < 2; rr++) {
      const int o    = rr * 4096 + o0;
      const int row  = o >> 6;
      const int colb = o & 63;
      const char* g = (const char*)Wb + (long)(bn + row) * ldr + (long)kt * 2 + colb;
      char* l = (char*)&sB[buf][0] + rr * 4096 + wave * 1024;
      __builtin_amdgcn_global_load_lds((const __attribute__((address_space(1))) void*)g,
                                       (__attribute__((address_space(3))) void*)l, 16, 0, 0);
    }
  };

  float4 xa[2];
  const int arow = tid >> 2;
  const int ac0  = (tid & 3) * 8;
  auto loadA = [&](int kt) {
    const float* g = x + (long)(bm + arow) * K + kt + ac0;
    xa[0] = *(const float4*)g;
    xa[1] = *(const float4*)(g + 4);
  };
  auto writeA = [&](int buf) {
    *(u16x8*)&sA[buf][arow * BK + ac0] = cvt8(xa[0], xa[1]);
  };

  f32x4 acc[2][4];
  #pragma unroll
  for (int i = 0; i < 2; i++)
    #pragma unroll
    for (int j = 0; j < 4; j++)
      acc[i][j] = f32x4{0.f, 0.f, 0.f, 0.f};

  loadA(0); writeA(0);
  stageB(0, 0);
  __syncthreads();

  const int NT = K / BK;
  for (int t = 0; t < NT; ++t) {
    const int cur = t & 1, nxt = cur ^ 1;
    const bool pf = (t + 1 < NT);
    if (pf) {
      loadA((t + 1) * BK);
      stageB(nxt, (t + 1) * BK);
    }
    bf16x8 af[2], bfr[4];
    #pragma unroll
    for (int i = 0; i < 2; i++)
      af[i] = *(const bf16x8*)&sA[cur][(wm * 32 + i * 16 + r) * BK + quad * 8];
    #pragma unroll
    for (int j = 0; j < 4; j++)
      bfr[j] = *(const bf16x8*)&sB[cur][(wn * 64 + j * 16 + r) * BK + quad * 8];
    #pragma unroll
    for (int i = 0; i < 2; i++)
      #pragma unroll
      for (int j = 0; j < 4; j++)
        acc[i][j] = __builtin_amdgcn_mfma_f32_16x16x32_bf16(af[i], bfr[j], acc[i][j], 0, 0, 0);
    if (pf) writeA(nxt);
    __syncthreads();
  }

  #pragma unroll
  for (int i = 0; i < 2; i++) {
    #pragma unroll
    for (int j = 0; j < 4; j++) {
      #pragma unroll
      for (int reg = 0; reg < 4; reg++) {
        const int row = bm + wm * 32 + i * 16 + quad * 4 + reg;
        const int col = bn + wn * 64 + j * 16 + r;
        float v = acc[i][j][reg];
        v = v > 0.f ? v : 0.f;
        const long idx = (long)row * N + col;
        key_f[idx]  = v;
        key_bf[idx] = f2bf_rne(v);
      }
    }
  }
}

// ===== GEMM2: NBUF=3 depth-2 counted-vmcnt (R9-verified), BN 128->64 =====
// R9 counters: MfmaUtil 19%, VALUBusy 16%, HBM 48%, Occupancy 22% => latency-
// bound, under-occupied. Parameter change only: BN=64 cuts LDS 48->36KB =>
// 4 blocks/CU (launch_bounds(256,4)); grid 1024->2048 (8-deep queue/CU).
// Loads/tile 4->3 => steady-state s_waitcnt vmcnt(3) (tile t+2 stays in flight).
#define G2_BM 128
#define G2_BN 64
#define NBUF 3

__global__ __launch_bounds__(256, 4)
void gemm2(const u16* __restrict__ A, const u16* __restrict__ B,
           float* __restrict__ C,
           int M, int N, int K,
           long sA_batch, long sB_batch, long sC_batch)
{
  __shared__ __align__(16) u16 sA[NBUF][G2_BM * BK];  // 3 x 8 KB
  __shared__ __align__(16) u16 sB[NBUF][G2_BN * BK];  // 3 x 4 KB
  const int tid  = threadIdx.x;
  const int wave = tid >> 6;
  const int lane = tid & 63;
  const int quad = lane >> 4;
  const int r    = lane & 15;
  const int wm   = wave >> 1;      // 0..1: 64-row half
  const int wn   = wave & 1;       // 0..1: 32-col half

  // XCD-chunked bijective swizzle: grid (16,16,8), batch bz -> XCD bz
  const int gx  = gridDim.x, gy = gridDim.y;
  const int nwg = gx * gy * (int)gridDim.z;
  const int id  = (int)blockIdx.x + gx * ((int)blockIdx.y + gy * (int)blockIdx.z);
  const int cpx = nwg >> 3;
  const int lid = (id & 7) * cpx + (id >> 3);
  const int bx  = lid % gx;
  const int tq  = lid / gx;
  const int by  = tq % gy;
  const int bz  = tq / gy;

  const int bm    = by * G2_BM;
  const int bn    = bx * G2_BN;
  const int batch = bz;

  const char* Asrc = (const char*)(A + (long)batch * sA_batch) + (long)bm * ((long)K * 2);
  const char* Bsrc = (const char*)(B + (long)batch * sB_batch) + (long)bn * ((long)K * 2);
  const long ldr = (long)K * 2;

  const int o0 = wave * 1024 + lane * 16;
  // A tile 128x32 bf16 = 8KB: 2 gload_lds/thread
  auto stageA = [&](int buf, int kt) {
    #pragma unroll
    for (int rr = 0; rr < 2; rr++) {
      const int o    = rr * 4096 + o0;
      const int row  = o >> 6;
      const int colb = o & 63;
      const char* g = Asrc + (long)row * ldr + (long)kt * 2 + colb;
      char* l = (char*)&sA[buf][0] + rr * 4096 + wave * 1024;
      __builtin_amdgcn_global_load_lds((const __attribute__((address_space(1))) void*)g,
                                       (__attribute__((address_space(3))) void*)l, 16, 0, 0);
    }
  };
  // B tile 64x32 bf16 = 4KB: 1 gload_lds/thread
  auto stageB = [&](int buf, int kt) {
    const int row  = o0 >> 6;
    const int colb = o0 & 63;
    const char* g = Bsrc + (long)row * ldr + (long)kt * 2 + colb;
    char* l = (char*)&sB[buf][0] + wave * 1024;
    __builtin_amdgcn_global_load_lds((const __attribute__((address_space(1))) void*)g,
                                     (__attribute__((address_space(3))) void*)l, 16, 0, 0);
  };

  f32x4 acc[4][2];
  #pragma unroll
  for (int i = 0; i < 4; i++)
    #pragma unroll
    for (int j = 0; j < 2; j++)
      acc[i][j] = f32x4{0.f, 0.f, 0.f, 0.f};

  // depth-2 prologue: tiles 0,1 in flight (6 loads); vmcnt(3) retires tile 0
  stageA(0, 0);  stageB(0, 0);
  stageA(1, BK); stageB(1, BK);
  asm volatile("s_waitcnt vmcnt(3)" ::: "memory");
  __builtin_amdgcn_s_barrier();
  __builtin_amdgcn_sched_barrier(0);

  const int NT = K / BK;   // 8
  for (int t = 0; t < NT; ++t) {
    const int cur = t % 3;
    if (t + 2 < NT) {
      const int nb = (t + 2) % 3;
      stageA(nb, (t + 2) * BK);
      stageB(nb, (t + 2) * BK);
    }
    bf16x8 af[4], bfr[2];
    #pragma unroll
    for (int i = 0; i < 4; i++)
      af[i] = *(const bf16x8*)&sA[cur][(wm * 64 + i * 16 + r) * BK + quad * 8];
    #pragma unroll
    for (int j = 0; j < 2; j++)
      bfr[j] = *(const bf16x8*)&sB[cur][(wn * 32 + j * 16 + r) * BK + quad * 8];
    #pragma unroll
    for (int i = 0; i < 4; i++)
      #pragma unroll
      for (int j = 0; j < 2; j++)
        acc[i][j] = __builtin_amdgcn_mfma_f32_16x16x32_bf16(af[i], bfr[j], acc[i][j], 0, 0, 0);
    if (t + 1 < NT) {
      // retire tile t+1 before barrier; leave tile t+2's 3 loads in flight
      if (t + 2 < NT) asm volatile("s_waitcnt vmcnt(3)" ::: "memory");
      else            asm volatile("s_waitcnt vmcnt(0)" ::: "memory");
      __builtin_amdgcn_s_barrier();
      __builtin_amdgcn_sched_barrier(0);
    }
  }

  float* Co = C + (long)batch * sC_batch;
  #pragma unroll
  for (int i = 0; i < 4; i++) {
    #pragma unroll
    for (int j = 0; j < 2; j++) {
      #pragma unroll
      for (int reg = 0; reg < 4; reg++) {
        const int row = bm + wm * 64 + i * 16 + quad * 4 + reg;
        const int col = bn + wn * 32 + j * 16 + r;
        Co[(long)row * N + col] = acc[i][j][reg];
      }
    }
  }
}

extern "C" void kernel_launch(void* const* d_in, const int* in_sizes, int n_in,
                              void* d_out, int out_size, void* d_ws, size_t ws_size,
                              hipStream_t stream) {
  const float* x   = (const float*)d_in[0];
  const float* mem = (const float*)d_in[1];
  const float* W   = (const float*)d_in[2];
  float* out   = (float*)d_out;
  float* key_f = out;
  float* val_f = out + NX;
  u16* ws     = (u16*)d_ws;
  u16* W_bf   = ws;
  u16* mem_bf = ws + WS_MEM;
  u16* key_bf = ws + WS_KEY;

  convert_bf16_kernel<<<(int)((NW + NM) / 8 / 256), 256, 0, stream>>>(mem, W, ws);

  dim3 g1(256 / G1_BN, 16384 / G1_BM, 1);
  gemm1_x<<<g1, 256, 0, stream>>>(x, W_bf, key_f, key_bf);

  dim3 g2(1024 / G2_BN, 2048 / G2_BM, 8);   // (16,16,8) = 2048 blocks
  gemm2<<<g2, 256, 0, stream>>>(key_bf, mem_bf, val_f,
                                2048, 1024, 256,
                                (long)2048 * 256, (long)1024 * 256,
                                (long)2048 * 1024);
}

// Round 14
// 125.093 us; speedup vs baseline: 1.9141x; 1.0109x over previous
//
#include <hip/hip_runtime.h>
#include <cstdint>

typedef unsigned short u16;
typedef __bf16 bf16x8 __attribute__((ext_vector_type(8)));
typedef float f32x4 __attribute__((ext_vector_type(4)));
typedef u16 u16x8 __attribute__((ext_vector_type(8)));

// Problem sizes: B=8, S=2048, I=256, H=256, M=1024
#define NX 4194304L   // x / key elems
#define NM 2097152L   // mem elems
// ws layout (u16): [mem_bf 0..NM) [key_bf NM..NM+NX)

__device__ __forceinline__ u16 f2bf_rne(float f) {
  union { float f; uint32_t u; } v; v.f = f;
  uint32_t r = v.u + 0x7fffu + ((v.u >> 16) & 1u);
  return (u16)(r >> 16);
}

__device__ __forceinline__ u16x8 cvt8(float4 a, float4 b) {
  u16x8 o;
  o[0]=f2bf_rne(a.x); o[1]=f2bf_rne(a.y); o[2]=f2bf_rne(a.z); o[3]=f2bf_rne(a.w);
  o[4]=f2bf_rne(b.x); o[5]=f2bf_rne(b.y); o[6]=f2bf_rne(b.z); o[7]=f2bf_rne(b.w);
  return o;
}

// ========== Fused dispatch 1: GEMM1 (512 blocks) + mem->bf16 conv (1024 blocks) ==
// GEMM1 key = relu(x @ W^T): R7-verified structure (BM=64, 2 blk/CU), but W is
// now reg-staged from fp32 (same cvt path as x; W panels 128KB, L2-hot) so the
// mem-conversion can ride in the same dispatch with no producer-consumer race.
// Conv blocks (bid>=512) run concurrently on spare block slots -> conv time and
// one launch gap disappear from the serial critical path.
#define G1_BM 64
#define G1_BN 128
#define BK 32
#define G1_BLOCKS 512

__global__ __launch_bounds__(256, 2)
void g1_fused(const float* __restrict__ x, const float* __restrict__ W,
              const float* __restrict__ mem,
              float* __restrict__ key_f, u16* __restrict__ key_bf,
              u16* __restrict__ mem_bf)
{
  const int bid = blockIdx.x;
  const int tid = threadIdx.x;

  if (bid >= G1_BLOCKS) {
    // ---- mem fp32 -> bf16: 1024 blocks x 256 thr x 8 elems (exact cover) ----
    long e = ((long)(bid - G1_BLOCKS) * 256 + tid) * 8;
    float4 f0 = *(const float4*)(mem + e);
    float4 f1 = *(const float4*)(mem + e + 4);
    *(u16x8*)(mem_bf + e) = cvt8(f0, f1);
    return;
  }

  // ---- GEMM1 ----
  const int K = 256, N = 256;
  __shared__ __align__(16) u16 sA[2][G1_BM * BK];   // 2 x 4 KB
  __shared__ __align__(16) u16 sB[2][G1_BN * BK];   // 2 x 8 KB
  const int wave = tid >> 6;
  const int lane = tid & 63;
  const int quad = lane >> 4;
  const int r    = lane & 15;
  const int wm   = wave >> 1;
  const int wn   = wave & 1;

  // XCD-chunked bijective swizzle over the 512 G1 blocks (logical grid 2x256)
  const int cpx = G1_BLOCKS >> 3;
  const int lid = (bid & 7) * cpx + (bid >> 3);
  const int bm  = (lid >> 1) * G1_BM;
  const int bn  = (lid & 1) * G1_BN;

  // A (x) staging: 64x32 fp32 tile; thread t: row t>>2, cols (t&3)*8..+8
  float4 xa[2];
  const int arow = tid >> 2;
  const int ac0  = (tid & 3) * 8;
  auto loadA = [&](int kt) {
    const float* g = x + (long)(bm + arow) * K + kt + ac0;
    xa[0] = *(const float4*)g;
    xa[1] = *(const float4*)(g + 4);
  };
  auto writeA = [&](int buf) {
    *(u16x8*)&sA[buf][arow * BK + ac0] = cvt8(xa[0], xa[1]);
  };

  // B (W) staging: 128x32 fp32 tile; thread t: row t>>1, cols (t&1)*16..+16
  float4 xb[4];
  const int brow = tid >> 1;
  const int bc0  = (tid & 1) * 16;
  auto loadB = [&](int kt) {
    const float* g = W + (long)(bn + brow) * K + kt + bc0;
    #pragma unroll
    for (int c = 0; c < 4; c++) xb[c] = *(const float4*)(g + c * 4);
  };
  auto writeB = [&](int buf) {
    u16* d = &sB[buf][brow * BK + bc0];
    *(u16x8*)d       = cvt8(xb[0], xb[1]);
    *(u16x8*)(d + 8) = cvt8(xb[2], xb[3]);
  };

  f32x4 acc[2][4];
  #pragma unroll
  for (int i = 0; i < 2; i++)
    #pragma unroll
    for (int j = 0; j < 4; j++)
      acc[i][j] = f32x4{0.f, 0.f, 0.f, 0.f};

  loadA(0); loadB(0);
  writeA(0); writeB(0);
  __syncthreads();

  const int NT = K / BK;   // 8
  for (int t = 0; t < NT; ++t) {
    const int cur = t & 1, nxt = cur ^ 1;
    const bool pf = (t + 1 < NT);
    if (pf) {                       // issue next tile's global fp32 loads first
      loadA((t + 1) * BK);
      loadB((t + 1) * BK);
    }
    bf16x8 af[2], bfr[4];
    #pragma unroll
    for (int i = 0; i < 2; i++)
      af[i] = *(const bf16x8*)&sA[cur][(wm * 32 + i * 16 + r) * BK + quad * 8];
    #pragma unroll
    for (int j = 0; j < 4; j++)
      bfr[j] = *(const bf16x8*)&sB[cur][(wn * 64 + j * 16 + r) * BK + quad * 8];
    #pragma unroll
    for (int i = 0; i < 2; i++)
      #pragma unroll
      for (int j = 0; j < 4; j++)
        acc[i][j] = __builtin_amdgcn_mfma_f32_16x16x32_bf16(af[i], bfr[j], acc[i][j], 0, 0, 0);
    if (pf) {                       // cvt + LDS write after the MFMAs
      writeA(nxt);
      writeB(nxt);
    }
    __syncthreads();
  }

  // epilogue: C/D layout col=lane&15, row=quad*4+reg (verified m89/m91)
  #pragma unroll
  for (int i = 0; i < 2; i++) {
    #pragma unroll
    for (int j = 0; j < 4; j++) {
      #pragma unroll
      for (int reg = 0; reg < 4; reg++) {
        const int row = bm + wm * 32 + i * 16 + quad * 4 + reg;
        const int col = bn + wn * 64 + j * 16 + r;
        float v = acc[i][j][reg];
        v = v > 0.f ? v : 0.f;
        const long idx = (long)row * N + col;
        key_f[idx]  = v;
        key_bf[idx] = f2bf_rne(v);
      }
    }
  }
}

// ===== GEMM2: val_b = key_b @ mem_b^T — R9-measured best (BN=128, NBUF=3, =====
// depth-2 counted vmcnt(4)). R12 proved BN=64 regresses (staging ratio).
#define G2_BM 128
#define G2_BN 128
#define NBUF 3

__global__ __launch_bounds__(256, 3)
void gemm2(const u16* __restrict__ A, const u16* __restrict__ B,
           float* __restrict__ C,
           int M, int N, int K,
           long sA_batch, long sB_batch, long sC_batch)
{
  __shared__ __align__(16) u16 sA[NBUF][G2_BM * BK];  // 3 x 8 KB
  __shared__ __align__(16) u16 sB[NBUF][G2_BN * BK];  // 3 x 8 KB
  const int tid  = threadIdx.x;
  const int wave = tid >> 6;
  const int lane = tid & 63;
  const int quad = lane >> 4;
  const int r    = lane & 15;
  const int wm   = wave >> 1;
  const int wn   = wave & 1;

  // XCD-chunked bijective swizzle: grid (8,16,8), batch bz -> XCD bz
  const int gx  = gridDim.x, gy = gridDim.y;
  const int nwg = gx * gy * (int)gridDim.z;
  const int id  = (int)blockIdx.x + gx * ((int)blockIdx.y + gy * (int)blockIdx.z);
  const int cpx = nwg >> 3;
  const int lid = (id & 7) * cpx + (id >> 3);
  const int bx  = lid % gx;
  const int tq  = lid / gx;
  const int by  = tq % gy;
  const int bz  = tq / gy;

  const int bm    = by * G2_BM;
  const int bn    = bx * G2_BN;
  const int batch = bz;

  const long ldr = (long)K * 2;
  const char* Asrc = (const char*)(A + (long)batch * sA_batch) + (long)bm * ldr;
  const char* Bsrc = (const char*)(B + (long)batch * sB_batch) + (long)bn * ldr;

  const int o0 = wave * 1024 + lane * 16;
  auto stage = [&](u16* dst, const char* src, int kt) {
    #pragma unroll
    for (int rr = 0; rr < 2; rr++) {
      const int o    = rr * 4096 + o0;
      const int row  = o >> 6;
      const int colb = o & 63;
      const char* g = src + (long)row * ldr + (long)kt * 2 + colb;
      char* l = (char*)dst + rr * 4096 + wave * 1024;
      __builtin_amdgcn_global_load_lds((const __attribute__((address_space(1))) void*)g,
                                       (__attribute__((address_space(3))) void*)l, 16, 0, 0);
    }
  };

  f32x4 acc[4][4];
  #pragma unroll
  for (int i = 0; i < 4; i++)
    #pragma unroll
    for (int j = 0; j < 4; j++)
      acc[i][j] = f32x4{0.f, 0.f, 0.f, 0.f};

  // depth-2 prologue: tiles 0,1 in flight (8 loads); vmcnt(4) retires tile 0
  stage(&sA[0][0], Asrc, 0);  stage(&sB[0][0], Bsrc, 0);
  stage(&sA[1][0], Asrc, BK); stage(&sB[1][0], Bsrc, BK);
  asm volatile("s_waitcnt vmcnt(4)" ::: "memory");
  __builtin_amdgcn_s_barrier();
  __builtin_amdgcn_sched_barrier(0);

  const int NT = K / BK;   // 8
  for (int t = 0; t < NT; ++t) {
    const int cur = t % 3;
    if (t + 2 < NT) {
      const int nb = (t + 2) % 3;
      stage(&sA[nb][0], Asrc, (t + 2) * BK);
      stage(&sB[nb][0], Bsrc, (t + 2) * BK);
    }
    bf16x8 af[4], bfr[4];
    #pragma unroll
    for (int i = 0; i < 4; i++)
      af[i] = *(const bf16x8*)&sA[cur][(wm * 64 + i * 16 + r) * BK + quad * 8];
    #pragma unroll
    for (int j = 0; j < 4; j++)
      bfr[j] = *(const bf16x8*)&sB[cur][(wn * 64 + j * 16 + r) * BK + quad * 8];
    #pragma unroll
    for (int i = 0; i < 4; i++)
      #pragma unroll
      for (int j = 0; j < 4; j++)
        acc[i][j] = __builtin_amdgcn_mfma_f32_16x16x32_bf16(af[i], bfr[j], acc[i][j], 0, 0, 0);
    if (t + 1 < NT) {
      // retire tile t+1 before barrier; leave tile t+2's 4 loads in flight
      if (t + 2 < NT) asm volatile("s_waitcnt vmcnt(4)" ::: "memory");
      else            asm volatile("s_waitcnt vmcnt(0)" ::: "memory");
      __builtin_amdgcn_s_barrier();
      __builtin_amdgcn_sched_barrier(0);
    }
  }

  float* Co = C + (long)batch * sC_batch;
  #pragma unroll
  for (int i = 0; i < 4; i++) {
    #pragma unroll
    for (int j = 0; j < 4; j++) {
      #pragma unroll
      for (int reg = 0; reg < 4; reg++) {
        const int row = bm + wm * 64 + i * 16 + quad * 4 + reg;
        const int col = bn + wn * 64 + j * 16 + r;
        Co[(long)row * N + col] = acc[i][j][reg];
      }
    }
  }
}

extern "C" void kernel_launch(void* const* d_in, const int* in_sizes, int n_in,
                              void* d_out, int out_size, void* d_ws, size_t ws_size,
                              hipStream_t stream) {
  const float* x   = (const float*)d_in[0];  // (8,2048,256) fp32
  const float* mem = (const float*)d_in[1];  // (8,1024,256) fp32
  const float* W   = (const float*)d_in[2];  // (256,256)    fp32
  float* out   = (float*)d_out;
  float* key_f = out;            // (16384,256)
  float* val_f = out + NX;       // (8,2048,1024)
  u16* ws     = (u16*)d_ws;
  u16* mem_bf = ws;              // NM elems
  u16* key_bf = ws + NM;         // NX elems

  // 1) fused: GEMM1 (512 blocks) + mem conversion (1024 blocks), one dispatch
  g1_fused<<<G1_BLOCKS + (int)(NM / 2048), 256, 0, stream>>>(
      x, W, mem, key_f, key_bf, mem_bf);

  // 2) val_b = key_b @ mem_b^T: per batch M=2048, N=1024, K=256
  dim3 g2(1024 / G2_BN, 2048 / G2_BM, 8);   // (8,16,8) = 1024 blocks
  gemm2<<<g2, 256, 0, stream>>>(key_bf, mem_bf, val_f,
                                2048, 1024, 256,
                                (long)2048 * 256, (long)1024 * 256,
                                (long)2048 * 1024);
}

// Round 17
// 124.109 us; speedup vs baseline: 1.9293x; 1.0079x over previous
//
#include <hip/hip_runtime.h>
#include <cstdint>

typedef unsigned short u16;
typedef __bf16 bf16x8 __attribute__((ext_vector_type(8)));
typedef float f32x4 __attribute__((ext_vector_type(4)));
typedef u16 u16x8 __attribute__((ext_vector_type(8)));

// Problem sizes: B=8, S=2048, I=256, H=256, M=1024
#define NX 4194304L   // x / key elems
#define NM 2097152L   // mem elems
// ws layout (u16): [mem_bf 0..NM) [key_bf NM..NM+NX)

// T2 LDS swizzle (rule #21: LDS linear, swizzle global src + read addr):
// physical 16B-chunk = logical_chunk ^ ((row>>1)&3). Spreads the 16-row
// column-slice ds_read_b128 pattern from 8-way to 2-way (free) bank aliasing.
#define SWZ(row, j) ((j) ^ (((row) >> 1) & 3))

__device__ __forceinline__ u16 f2bf_rne(float f) {
  union { float f; uint32_t u; } v; v.f = f;
  uint32_t r = v.u + 0x7fffu + ((v.u >> 16) & 1u);
  return (u16)(r >> 16);
}

__device__ __forceinline__ u16x8 cvt8(float4 a, float4 b) {
  u16x8 o;
  o[0]=f2bf_rne(a.x); o[1]=f2bf_rne(a.y); o[2]=f2bf_rne(a.z); o[3]=f2bf_rne(a.w);
  o[4]=f2bf_rne(b.x); o[5]=f2bf_rne(b.y); o[6]=f2bf_rne(b.z); o[7]=f2bf_rne(b.w);
  return o;
}

// ========== Fused dispatch 1: GEMM1 (512 blocks) + mem->bf16 conv (1024 blocks) ==
#define G1_BM 64
#define G1_BN 128
#define BK 32
#define G1_BLOCKS 512

__global__ __launch_bounds__(256, 2)
void g1_fused(const float* __restrict__ x, const float* __restrict__ W,
              const float* __restrict__ mem,
              float* __restrict__ key_f, u16* __restrict__ key_bf,
              u16* __restrict__ mem_bf)
{
  const int bid = blockIdx.x;
  const int tid = threadIdx.x;

  if (bid >= G1_BLOCKS) {
    // ---- mem fp32 -> bf16: 1024 blocks x 256 thr x 8 elems (exact cover) ----
    long e = ((long)(bid - G1_BLOCKS) * 256 + tid) * 8;
    float4 f0 = *(const float4*)(mem + e);
    float4 f1 = *(const float4*)(mem + e + 4);
    *(u16x8*)(mem_bf + e) = cvt8(f0, f1);
    return;
  }

  // ---- GEMM1: key = relu(x @ W^T), both operands reg-staged fp32->bf16 ----
  const int K = 256, N = 256;
  __shared__ __align__(16) u16 sA[2][G1_BM * BK];   // 2 x 4 KB
  __shared__ __align__(16) u16 sB[2][G1_BN * BK];   // 2 x 8 KB
  const int wave = tid >> 6;
  const int lane = tid & 63;
  const int quad = lane >> 4;
  const int r    = lane & 15;
  const int wm   = wave >> 1;
  const int wn   = wave & 1;

  // XCD-chunked bijective swizzle over the 512 G1 blocks (logical grid 2x256)
  const int cpx = G1_BLOCKS >> 3;
  const int lid = (bid & 7) * cpx + (bid >> 3);
  const int bm  = (lid >> 1) * G1_BM;
  const int bn  = (lid & 1) * G1_BN;

  // A (x) staging: 64x32 fp32 tile; thread t: row t>>2, 16B chunk j=t&3
  float4 xa[2];
  const int arow = tid >> 2;
  const int aj   = tid & 3;
  auto loadA = [&](int kt) {
    const float* g = x + (long)(bm + arow) * K + kt + aj * 8;
    xa[0] = *(const float4*)g;
    xa[1] = *(const float4*)(g + 4);
  };
  auto writeA = [&](int buf) {   // ds_write at swizzled chunk
    *(u16x8*)&sA[buf][arow * BK + SWZ(arow, aj) * 8] = cvt8(xa[0], xa[1]);
  };

  // B (W) staging: 128x32 fp32 tile; thread t: row t>>1, chunks {2*(t&1), +1}
  float4 xb[4];
  const int brow = tid >> 1;
  const int bj0  = (tid & 1) * 2;
  auto loadB = [&](int kt) {
    const float* g = W + (long)(bn + brow) * K + kt + bj0 * 8;
    #pragma unroll
    for (int c = 0; c < 4; c++) xb[c] = *(const float4*)(g + c * 4);
  };
  auto writeB = [&](int buf) {   // split 32B into two swizzled 16B stores
    u16* base = &sB[buf][brow * BK];
    *(u16x8*)(base + SWZ(brow, bj0)     * 8) = cvt8(xb[0], xb[1]);
    *(u16x8*)(base + SWZ(brow, bj0 + 1) * 8) = cvt8(xb[2], xb[3]);
  };

  f32x4 acc[2][4];
  #pragma unroll
  for (int i = 0; i < 2; i++)
    #pragma unroll
    for (int j = 0; j < 4; j++)
      acc[i][j] = f32x4{0.f, 0.f, 0.f, 0.f};

  loadA(0); loadB(0);
  writeA(0); writeB(0);
  __syncthreads();

  const int NT = K / BK;   // 8
  for (int t = 0; t < NT; ++t) {
    const int cur = t & 1, nxt = cur ^ 1;
    const bool pf = (t + 1 < NT);
    if (pf) {                       // issue next tile's global fp32 loads first
      loadA((t + 1) * BK);
      loadB((t + 1) * BK);
    }
    bf16x8 af[2], bfr[4];
    #pragma unroll
    for (int i = 0; i < 2; i++) {
      const int row = wm * 32 + i * 16 + r;
      af[i] = *(const bf16x8*)&sA[cur][row * BK + SWZ(row, quad) * 8];
    }
    #pragma unroll
    for (int j = 0; j < 4; j++) {
      const int row = wn * 64 + j * 16 + r;
      bfr[j] = *(const bf16x8*)&sB[cur][row * BK + SWZ(row, quad) * 8];
    }
    #pragma unroll
    for (int i = 0; i < 2; i++)
      #pragma unroll
      for (int j = 0; j < 4; j++)
        acc[i][j] = __builtin_amdgcn_mfma_f32_16x16x32_bf16(af[i], bfr[j], acc[i][j], 0, 0, 0);
    if (pf) {                       // cvt + LDS write after the MFMAs
      writeA(nxt);
      writeB(nxt);
    }
    __syncthreads();
  }

  // epilogue: C/D layout col=lane&15, row=quad*4+reg (verified m89/m91)
  #pragma unroll
  for (int i = 0; i < 2; i++) {
    #pragma unroll
    for (int j = 0; j < 4; j++) {
      #pragma unroll
      for (int reg = 0; reg < 4; reg++) {
        const int row = bm + wm * 32 + i * 16 + quad * 4 + reg;
        const int col = bn + wn * 64 + j * 16 + r;
        float v = acc[i][j][reg];
        v = v > 0.f ? v : 0.f;
        const long idx = (long)row * N + col;
        key_f[idx]  = v;
        key_bf[idx] = f2bf_rne(v);
      }
    }
  }
}

// ===== GEMM2: val_b = key_b @ mem_b^T — NBUF=3 depth-2 counted vmcnt(4), =====
// BN=128 (R9-best), + T2 swizzle: pre-swizzled per-lane GLOBAL src chunk
// (gload_lds writes LDS linearly) + matching XOR on ds_read addrs.
#define G2_BM 128
#define G2_BN 128
#define NBUF 3

__global__ __launch_bounds__(256, 3)
void gemm2(const u16* __restrict__ A, const u16* __restrict__ B,
           float* __restrict__ C,
           int M, int N, int K,
           long sA_batch, long sB_batch, long sC_batch)
{
  __shared__ __align__(16) u16 sA[NBUF][G2_BM * BK];  // 3 x 8 KB
  __shared__ __align__(16) u16 sB[NBUF][G2_BN * BK];  // 3 x 8 KB
  const int tid  = threadIdx.x;
  const int wave = tid >> 6;
  const int lane = tid & 63;
  const int quad = lane >> 4;
  const int r    = lane & 15;
  const int wm   = wave >> 1;
  const int wn   = wave & 1;

  // XCD-chunked bijective swizzle: grid (8,16,8), batch bz -> XCD bz
  const int gx  = gridDim.x, gy = gridDim.y;
  const int nwg = gx * gy * (int)gridDim.z;
  const int id  = (int)blockIdx.x + gx * ((int)blockIdx.y + gy * (int)blockIdx.z);
  const int cpx = nwg >> 3;
  const int lid = (id & 7) * cpx + (id >> 3);
  const int bx  = lid % gx;
  const int tq  = lid / gx;
  const int by  = tq % gy;
  const int bz  = tq / gy;

  const int bm    = by * G2_BM;
  const int bn    = bx * G2_BN;
  const int batch = bz;

  const long ldr = (long)K * 2;
  const char* Asrc = (const char*)(A + (long)batch * sA_batch) + (long)bm * ldr;
  const char* Bsrc = (const char*)(B + (long)batch * sB_batch) + (long)bn * ldr;

  const int o0 = wave * 1024 + lane * 16;
  // physical (linear) chunk this lane's gload_lds lands in: (row, jl).
  // fetch the LOGICAL chunk jl^m from global so LDS holds the swizzled layout.
  auto stage = [&](u16* dst, const char* src, int kt) {
    #pragma unroll
    for (int rr = 0; rr < 2; rr++) {
      const int o    = rr * 4096 + o0;
      const int row  = o >> 6;
      const int jl   = (o >> 4) & 3;
      const char* g = src + (long)row * ldr + (long)kt * 2 + SWZ(row, jl) * 16;
      char* l = (char*)dst + rr * 4096 + wave * 1024;
      __builtin_amdgcn_global_load_lds((const __attribute__((address_space(1))) void*)g,
                                       (__attribute__((address_space(3))) void*)l, 16, 0, 0);
    }
  };

  f32x4 acc[4][4];
  #pragma unroll
  for (int i = 0; i < 4; i++)
    #pragma unroll
    for (int j = 0; j < 4; j++)
      acc[i][j] = f32x4{0.f, 0.f, 0.f, 0.f};

  // depth-2 prologue: tiles 0,1 in flight (8 loads); vmcnt(4) retires tile 0
  stage(&sA[0][0], Asrc, 0);  stage(&sB[0][0], Bsrc, 0);
  stage(&sA[1][0], Asrc, BK); stage(&sB[1][0], Bsrc, BK);
  asm volatile("s_waitcnt vmcnt(4)" ::: "memory");
  __builtin_amdgcn_s_barrier();
  __builtin_amdgcn_sched_barrier(0);

  const int NT = K / BK;   // 8
  for (int t = 0; t < NT; ++t) {
    const int cur = t % 3;
    if (t + 2 < NT) {
      const int nb = (t + 2) % 3;
      stage(&sA[nb][0], Asrc, (t + 2) * BK);
      stage(&sB[nb][0], Bsrc, (t + 2) * BK);
    }
    bf16x8 af[4], bfr[4];
    #pragma unroll
    for (int i = 0; i < 4; i++) {
      const int row = wm * 64 + i * 16 + r;
      af[i] = *(const bf16x8*)&sA[cur][row * BK + SWZ(row, quad) * 8];
    }
    #pragma unroll
    for (int j = 0; j < 4; j++) {
      const int row = wn * 64 + j * 16 + r;
      bfr[j] = *(const bf16x8*)&sB[cur][row * BK + SWZ(row, quad) * 8];
    }
    #pragma unroll
    for (int i = 0; i < 4; i++)
      #pragma unroll
      for (int j = 0; j < 4; j++)
        acc[i][j] = __builtin_amdgcn_mfma_f32_16x16x32_bf16(af[i], bfr[j], acc[i][j], 0, 0, 0);
    if (t + 1 < NT) {
      // retire tile t+1 before barrier; leave tile t+2's 4 loads in flight
      if (t + 2 < NT) asm volatile("s_waitcnt vmcnt(4)" ::: "memory");
      else            asm volatile("s_waitcnt vmcnt(0)" ::: "memory");
      __builtin_amdgcn_s_barrier();
      __builtin_amdgcn_sched_barrier(0);
    }
  }

  float* Co = C + (long)batch * sC_batch;
  #pragma unroll
  for (int i = 0; i < 4; i++) {
    #pragma unroll
    for (int j = 0; j < 4; j++) {
      #pragma unroll
      for (int reg = 0; reg < 4; reg++) {
        const int row = bm + wm * 64 + i * 16 + quad * 4 + reg;
        const int col = bn + wn * 64 + j * 16 + r;
        Co[(long)row * N + col] = acc[i][j][reg];
      }
    }
  }
}

extern "C" void kernel_launch(void* const* d_in, const int* in_sizes, int n_in,
                              void* d_out, int out_size, void* d_ws, size_t ws_size,
                              hipStream_t stream) {
  const float* x   = (const float*)d_in[0];  // (8,2048,256) fp32
  const float* mem = (const float*)d_in[1];  // (8,1024,256) fp32
  const float* W   = (const float*)d_in[2];  // (256,256)    fp32
  float* out   = (float*)d_out;
  float* key_f = out;            // (16384,256)
  float* val_f = out + NX;       // (8,2048,1024)
  u16* ws     = (u16*)d_ws;
  u16* mem_bf = ws;              // NM elems
  u16* key_bf = ws + NM;         // NX elems

  // 1) fused: GEMM1 (512 blocks) + mem conversion (1024 blocks), one dispatch
  g1_fused<<<G1_BLOCKS + (int)(NM / 2048), 256, 0, stream>>>(
      x, W, mem, key_f, key_bf, mem_bf);

  // 2) val_b = key_b @ mem_b^T: per batch M=2048, N=1024, K=256
  dim3 g2(1024 / G2_BN, 2048 / G2_BM, 8);   // (8,16,8) = 1024 blocks
  gemm2<<<g2, 256, 0, stream>>>(key_bf, mem_bf, val_f,
                                2048, 1024, 256,
                                (long)2048 * 256, (long)1024 * 256,
                                (long)2048 * 1024);
}

// Round 19
// 123.887 us; speedup vs baseline: 1.9328x; 1.0018x over previous
//
#include <hip/hip_runtime.h>
#include <cstdint>

typedef unsigned short u16;
typedef __bf16 bf16x8 __attribute__((ext_vector_type(8)));
typedef float f32x4 __attribute__((ext_vector_type(4)));
typedef u16 u16x8 __attribute__((ext_vector_type(8)));

// Problem sizes: B=8, S=2048, I=256, H=256, M=1024
#define NX 4194304L   // x / key elems
#define NM 2097152L   // mem elems
// ws layout (u16): [mem_bf 0..NM) [key_bf NM..NM+NX)

// T2 LDS swizzle (rule #21: both-sides): physical 16B-chunk = logical ^ ((row>>1)&3)
#define SWZ(row, j) ((j) ^ (((row) >> 1) & 3))

__device__ __forceinline__ u16 f2bf_rne(float f) {
  union { float f; uint32_t u; } v; v.f = f;
  uint32_t r = v.u + 0x7fffu + ((v.u >> 16) & 1u);
  return (u16)(r >> 16);
}

__device__ __forceinline__ u16x8 cvt8(float4 a, float4 b) {
  u16x8 o;
  o[0]=f2bf_rne(a.x); o[1]=f2bf_rne(a.y); o[2]=f2bf_rne(a.z); o[3]=f2bf_rne(a.w);
  o[4]=f2bf_rne(b.x); o[5]=f2bf_rne(b.y); o[6]=f2bf_rne(b.z); o[7]=f2bf_rne(b.w);
  return o;
}

// ========== Fused dispatch 1 (R17-verified, unchanged): GEMM1 + mem conv ==========
#define G1_BM 64
#define G1_BN 128
#define BK 32
#define G1_BLOCKS 512

__global__ __launch_bounds__(256, 2)
void g1_fused(const float* __restrict__ x, const float* __restrict__ W,
              const float* __restrict__ mem,
              float* __restrict__ key_f, u16* __restrict__ key_bf,
              u16* __restrict__ mem_bf)
{
  const int bid = blockIdx.x;
  const int tid = threadIdx.x;

  if (bid >= G1_BLOCKS) {
    long e = ((long)(bid - G1_BLOCKS) * 256 + tid) * 8;
    float4 f0 = *(const float4*)(mem + e);
    float4 f1 = *(const float4*)(mem + e + 4);
    *(u16x8*)(mem_bf + e) = cvt8(f0, f1);
    return;
  }

  const int K = 256, N = 256;
  __shared__ __align__(16) u16 sA[2][G1_BM * BK];
  __shared__ __align__(16) u16 sB[2][G1_BN * BK];
  const int wave = tid >> 6;
  const int lane = tid & 63;
  const int quad = lane >> 4;
  const int r    = lane & 15;
  const int wm   = wave >> 1;
  const int wn   = wave & 1;

  const int cpx = G1_BLOCKS >> 3;
  const int lid = (bid & 7) * cpx + (bid >> 3);
  const int bm  = (lid >> 1) * G1_BM;
  const int bn  = (lid & 1) * G1_BN;

  float4 xa[2];
  const int arow = tid >> 2;
  const int aj   = tid & 3;
  auto loadA = [&](int kt) {
    const float* g = x + (long)(bm + arow) * K + kt + aj * 8;
    xa[0] = *(const float4*)g;
    xa[1] = *(const float4*)(g + 4);
  };
  auto writeA = [&](int buf) {
    *(u16x8*)&sA[buf][arow * BK + SWZ(arow, aj) * 8] = cvt8(xa[0], xa[1]);
  };

  float4 xb[4];
  const int brow = tid >> 1;
  const int bj0  = (tid & 1) * 2;
  auto loadB = [&](int kt) {
    const float* g = W + (long)(bn + brow) * K + kt + bj0 * 8;
    #pragma unroll
    for (int c = 0; c < 4; c++) xb[c] = *(const float4*)(g + c * 4);
  };
  auto writeB = [&](int buf) {
    u16* base = &sB[buf][brow * BK];
    *(u16x8*)(base + SWZ(brow, bj0)     * 8) = cvt8(xb[0], xb[1]);
    *(u16x8*)(base + SWZ(brow, bj0 + 1) * 8) = cvt8(xb[2], xb[3]);
  };

  f32x4 acc[2][4];
  #pragma unroll
  for (int i = 0; i < 2; i++)
    #pragma unroll
    for (int j = 0; j < 4; j++)
      acc[i][j] = f32x4{0.f, 0.f, 0.f, 0.f};

  loadA(0); loadB(0);
  writeA(0); writeB(0);
  __syncthreads();

  const int NT = K / BK;
  for (int t = 0; t < NT; ++t) {
    const int cur = t & 1, nxt = cur ^ 1;
    const bool pf = (t + 1 < NT);
    if (pf) {
      loadA((t + 1) * BK);
      loadB((t + 1) * BK);
    }
    bf16x8 af[2], bfr[4];
    #pragma unroll
    for (int i = 0; i < 2; i++) {
      const int row = wm * 32 + i * 16 + r;
      af[i] = *(const bf16x8*)&sA[cur][row * BK + SWZ(row, quad) * 8];
    }
    #pragma unroll
    for (int j = 0; j < 4; j++) {
      const int row = wn * 64 + j * 16 + r;
      bfr[j] = *(const bf16x8*)&sB[cur][row * BK + SWZ(row, quad) * 8];
    }
    #pragma unroll
    for (int i = 0; i < 2; i++)
      #pragma unroll
      for (int j = 0; j < 4; j++)
        acc[i][j] = __builtin_amdgcn_mfma_f32_16x16x32_bf16(af[i], bfr[j], acc[i][j], 0, 0, 0);
    if (pf) {
      writeA(nxt);
      writeB(nxt);
    }
    __syncthreads();
  }

  #pragma unroll
  for (int i = 0; i < 2; i++) {
    #pragma unroll
    for (int j = 0; j < 4; j++) {
      #pragma unroll
      for (int reg = 0; reg < 4; reg++) {
        const int row = bm + wm * 32 + i * 16 + quad * 4 + reg;
        const int col = bn + wn * 64 + j * 16 + r;
        float v = acc[i][j][reg];
        v = v > 0.f ? v : 0.f;
        const long idx = (long)row * N + col;
        key_f[idx]  = v;
        key_bf[idx] = f2bf_rne(v);
      }
    }
  }
}

// ===== GEMM2: BM 128->256 (barrier/fixed-cost amortization test) =====
// R9/R12/R14/R17 span 18.2-21.5us across depth/BN variants; all latency/
// barrier-bound (MfmaUtil 19%, nothing saturated). At NT=8 the per-block
// prologue+epilogue+7 barriers are ~35% of block time. BM=256: 512 blocks
// (half the fixed costs), 32 MFMA/barrier (2x amortization). Cost: LDS
// 3x24KB=72KB -> 2 blk/CU (8 waves/CU vs 12). Win => barrier-bound confirmed;
// loss => wave-count-bound, parameter space exhausted, revert to R17.
#define G2_BM 256
#define G2_BN 128
#define NBUF 3

__global__ __launch_bounds__(256, 2)
void gemm2(const u16* __restrict__ A, const u16* __restrict__ B,
           float* __restrict__ C,
           int M, int N, int K,
           long sA_batch, long sB_batch, long sC_batch)
{
  __shared__ __align__(16) u16 sA[NBUF][G2_BM * BK];  // 3 x 16 KB
  __shared__ __align__(16) u16 sB[NBUF][G2_BN * BK];  // 3 x 8 KB
  const int tid  = threadIdx.x;
  const int wave = tid >> 6;
  const int lane = tid & 63;
  const int quad = lane >> 4;
  const int r    = lane & 15;
  const int wm   = wave >> 1;      // 0..1: 128-row half
  const int wn   = wave & 1;       // 0..1: 64-col half

  // XCD-chunked bijective swizzle: grid (8,8,8)=512, batch bz -> XCD bz
  const int gx  = gridDim.x, gy = gridDim.y;
  const int nwg = gx * gy * (int)gridDim.z;
  const int id  = (int)blockIdx.x + gx * ((int)blockIdx.y + gy * (int)blockIdx.z);
  const int cpx = nwg >> 3;
  const int lid = (id & 7) * cpx + (id >> 3);
  const int bx  = lid % gx;
  const int tq  = lid / gx;
  const int by  = tq % gy;
  const int bz  = tq / gy;

  const int bm    = by * G2_BM;
  const int bn    = bx * G2_BN;
  const int batch = bz;

  const long ldr = (long)K * 2;
  const char* Asrc = (const char*)(A + (long)batch * sA_batch) + (long)bm * ldr;
  const char* Bsrc = (const char*)(B + (long)batch * sB_batch) + (long)bn * ldr;

  const int o0 = wave * 1024 + lane * 16;
  // A tile 256x32 bf16 = 16KB: 4 gload_lds/thread; B tile 128x32 = 8KB: 2.
  // Pre-swizzled global src chunk (gload_lds writes LDS linearly).
  auto stageA = [&](u16* dst, int kt) {
    #pragma unroll
    for (int rr = 0; rr < 4; rr++) {
      const int o    = rr * 4096 + o0;
      const int row  = o >> 6;
      const int jl   = (o >> 4) & 3;
      const char* g = Asrc + (long)row * ldr + (long)kt * 2 + SWZ(row, jl) * 16;
      char* l = (char*)dst + rr * 4096 + wave * 1024;
      __builtin_amdgcn_global_load_lds((const __attribute__((address_space(1))) void*)g,
                                       (__attribute__((address_space(3))) void*)l, 16, 0, 0);
    }
  };
  auto stageB = [&](u16* dst, int kt) {
    #pragma unroll
    for (int rr = 0; rr < 2; rr++) {
      const int o    = rr * 4096 + o0;
      const int row  = o >> 6;
      const int jl   = (o >> 4) & 3;
      const char* g = Bsrc + (long)row * ldr + (long)kt * 2 + SWZ(row, jl) * 16;
      char* l = (char*)dst + rr * 4096 + wave * 1024;
      __builtin_amdgcn_global_load_lds((const __attribute__((address_space(1))) void*)g,
                                       (__attribute__((address_space(3))) void*)l, 16, 0, 0);
    }
  };

  f32x4 acc[8][4];
  #pragma unroll
  for (int i = 0; i < 8; i++)
    #pragma unroll
    for (int j = 0; j < 4; j++)
      acc[i][j] = f32x4{0.f, 0.f, 0.f, 0.f};

  // depth-2 prologue: tiles 0,1 in flight (12 loads); vmcnt(6) retires tile 0
  stageA(&sA[0][0], 0);  stageB(&sB[0][0], 0);
  stageA(&sA[1][0], BK); stageB(&sB[1][0], BK);
  asm volatile("s_waitcnt vmcnt(6)" ::: "memory");
  __builtin_amdgcn_s_barrier();
  __builtin_amdgcn_sched_barrier(0);

  const int NT = K / BK;   // 8
  for (int t = 0; t < NT; ++t) {
    const int cur = t % 3;
    if (t + 2 < NT) {
      const int nb = (t + 2) % 3;
      stageA(&sA[nb][0], (t + 2) * BK);
      stageB(&sB[nb][0], (t + 2) * BK);
    }
    bf16x8 af[8], bfr[4];
    #pragma unroll
    for (int i = 0; i < 8; i++) {
      const int row = wm * 128 + i * 16 + r;
      af[i] = *(const bf16x8*)&sA[cur][row * BK + SWZ(row, quad) * 8];
    }
    #pragma unroll
    for (int j = 0; j < 4; j++) {
      const int row = wn * 64 + j * 16 + r;
      bfr[j] = *(const bf16x8*)&sB[cur][row * BK + SWZ(row, quad) * 8];
    }
    #pragma unroll
    for (int i = 0; i < 8; i++)
      #pragma unroll
      for (int j = 0; j < 4; j++)
        acc[i][j] = __builtin_amdgcn_mfma_f32_16x16x32_bf16(af[i], bfr[j], acc[i][j], 0, 0, 0);
    if (t + 1 < NT) {
      // retire tile t+1 before barrier; leave tile t+2's 6 loads in flight
      if (t + 2 < NT) asm volatile("s_waitcnt vmcnt(6)" ::: "memory");
      else            asm volatile("s_waitcnt vmcnt(0)" ::: "memory");
      __builtin_amdgcn_s_barrier();
      __builtin_amdgcn_sched_barrier(0);
    }
  }

  float* Co = C + (long)batch * sC_batch;
  #pragma unroll
  for (int i = 0; i < 8; i++) {
    #pragma unroll
    for (int j = 0; j < 4; j++) {
      #pragma unroll
      for (int reg = 0; reg < 4; reg++) {
        const int row = bm + wm * 128 + i * 16 + quad * 4 + reg;
        const int col = bn + wn * 64 + j * 16 + r;
        Co[(long)row * N + col] = acc[i][j][reg];
      }
    }
  }
}

extern "C" void kernel_launch(void* const* d_in, const int* in_sizes, int n_in,
                              void* d_out, int out_size, void* d_ws, size_t ws_size,
                              hipStream_t stream) {
  const float* x   = (const float*)d_in[0];  // (8,2048,256) fp32
  const float* mem = (const float*)d_in[1];  // (8,1024,256) fp32
  const float* W   = (const float*)d_in[2];  // (256,256)    fp32
  float* out   = (float*)d_out;
  float* key_f = out;            // (16384,256)
  float* val_f = out + NX;       // (8,2048,1024)
  u16* ws     = (u16*)d_ws;
  u16* mem_bf = ws;              // NM elems
  u16* key_bf = ws + NM;         // NX elems

  // 1) fused: GEMM1 (512 blocks) + mem conversion (1024 blocks), one dispatch
  g1_fused<<<G1_BLOCKS + (int)(NM / 2048), 256, 0, stream>>>(
      x, W, mem, key_f, key_bf, mem_bf);

  // 2) val_b = key_b @ mem_b^T: per batch M=2048, N=1024, K=256; BM=256
  dim3 g2(1024 / G2_BN, 2048 / G2_BM, 8);   // (8,8,8) = 512 blocks
  gemm2<<<g2, 256, 0, stream>>>(key_bf, mem_bf, val_f,
                                2048, 1024, 256,
                                (long)2048 * 256, (long)1024 * 256,
                                (long)2048 * 1024);
}

// Round 20
// 123.087 us; speedup vs baseline: 1.9453x; 1.0065x over previous
//
#include <hip/hip_runtime.h>
#include <cstdint>

typedef unsigned short u16;
typedef __bf16 bf16x8 __attribute__((ext_vector_type(8)));
typedef float f32x4 __attribute__((ext_vector_type(4)));
typedef u16 u16x8 __attribute__((ext_vector_type(8)));

// Problem sizes: B=8, S=2048, I=256, H=256, M=1024
#define NX 4194304L   // x / key elems
#define NM 2097152L   // mem elems
// ws layout (u16): [mem_bf 0..NM) [key_bf NM..NM+NX)

// T2 LDS swizzle (rule #21: both-sides): physical 16B-chunk = logical ^ ((row>>1)&3)
#define SWZ(row, j) ((j) ^ (((row) >> 1) & 3))

__device__ __forceinline__ u16 f2bf_rne(float f) {
  union { float f; uint32_t u; } v; v.f = f;
  uint32_t r = v.u + 0x7fffu + ((v.u >> 16) & 1u);
  return (u16)(r >> 16);
}

__device__ __forceinline__ u16x8 cvt8(float4 a, float4 b) {
  u16x8 o;
  o[0]=f2bf_rne(a.x); o[1]=f2bf_rne(a.y); o[2]=f2bf_rne(a.z); o[3]=f2bf_rne(a.w);
  o[4]=f2bf_rne(b.x); o[5]=f2bf_rne(b.y); o[6]=f2bf_rne(b.z); o[7]=f2bf_rne(b.w);
  return o;
}

// ========== Fused dispatch 1 (R17/R19-verified, unchanged): GEMM1 + mem conv ======
#define G1_BM 64
#define G1_BN 128
#define BK 32
#define G1_BLOCKS 512

__global__ __launch_bounds__(256, 2)
void g1_fused(const float* __restrict__ x, const float* __restrict__ W,
              const float* __restrict__ mem,
              float* __restrict__ key_f, u16* __restrict__ key_bf,
              u16* __restrict__ mem_bf)
{
  const int bid = blockIdx.x;
  const int tid = threadIdx.x;

  if (bid >= G1_BLOCKS) {
    long e = ((long)(bid - G1_BLOCKS) * 256 + tid) * 8;
    float4 f0 = *(const float4*)(mem + e);
    float4 f1 = *(const float4*)(mem + e + 4);
    *(u16x8*)(mem_bf + e) = cvt8(f0, f1);
    return;
  }

  const int K = 256, N = 256;
  __shared__ __align__(16) u16 sA[2][G1_BM * BK];
  __shared__ __align__(16) u16 sB[2][G1_BN * BK];
  const int wave = tid >> 6;
  const int lane = tid & 63;
  const int quad = lane >> 4;
  const int r    = lane & 15;
  const int wm   = wave >> 1;
  const int wn   = wave & 1;

  const int cpx = G1_BLOCKS >> 3;
  const int lid = (bid & 7) * cpx + (bid >> 3);
  const int bm  = (lid >> 1) * G1_BM;
  const int bn  = (lid & 1) * G1_BN;

  float4 xa[2];
  const int arow = tid >> 2;
  const int aj   = tid & 3;
  auto loadA = [&](int kt) {
    const float* g = x + (long)(bm + arow) * K + kt + aj * 8;
    xa[0] = *(const float4*)g;
    xa[1] = *(const float4*)(g + 4);
  };
  auto writeA = [&](int buf) {
    *(u16x8*)&sA[buf][arow * BK + SWZ(arow, aj) * 8] = cvt8(xa[0], xa[1]);
  };

  float4 xb[4];
  const int brow = tid >> 1;
  const int bj0  = (tid & 1) * 2;
  auto loadB = [&](int kt) {
    const float* g = W + (long)(bn + brow) * K + kt + bj0 * 8;
    #pragma unroll
    for (int c = 0; c < 4; c++) xb[c] = *(const float4*)(g + c * 4);
  };
  auto writeB = [&](int buf) {
    u16* base = &sB[buf][brow * BK];
    *(u16x8*)(base + SWZ(brow, bj0)     * 8) = cvt8(xb[0], xb[1]);
    *(u16x8*)(base + SWZ(brow, bj0 + 1) * 8) = cvt8(xb[2], xb[3]);
  };

  f32x4 acc[2][4];
  #pragma unroll
  for (int i = 0; i < 2; i++)
    #pragma unroll
    for (int j = 0; j < 4; j++)
      acc[i][j] = f32x4{0.f, 0.f, 0.f, 0.f};

  loadA(0); loadB(0);
  writeA(0); writeB(0);
  __syncthreads();

  const int NT = K / BK;
  for (int t = 0; t < NT; ++t) {
    const int cur = t & 1, nxt = cur ^ 1;
    const bool pf = (t + 1 < NT);
    if (pf) {
      loadA((t + 1) * BK);
      loadB((t + 1) * BK);
    }
    bf16x8 af[2], bfr[4];
    #pragma unroll
    for (int i = 0; i < 2; i++) {
      const int row = wm * 32 + i * 16 + r;
      af[i] = *(const bf16x8*)&sA[cur][row * BK + SWZ(row, quad) * 8];
    }
    #pragma unroll
    for (int j = 0; j < 4; j++) {
      const int row = wn * 64 + j * 16 + r;
      bfr[j] = *(const bf16x8*)&sB[cur][row * BK + SWZ(row, quad) * 8];
    }
    #pragma unroll
    for (int i = 0; i < 2; i++)
      #pragma unroll
      for (int j = 0; j < 4; j++)
        acc[i][j] = __builtin_amdgcn_mfma_f32_16x16x32_bf16(af[i], bfr[j], acc[i][j], 0, 0, 0);
    if (pf) {
      writeA(nxt);
      writeB(nxt);
    }
    __syncthreads();
  }

  #pragma unroll
  for (int i = 0; i < 2; i++) {
    #pragma unroll
    for (int j = 0; j < 4; j++) {
      #pragma unroll
      for (int reg = 0; reg < 4; reg++) {
        const int row = bm + wm * 32 + i * 16 + quad * 4 + reg;
        const int col = bn + wn * 64 + j * 16 + r;
        float v = acc[i][j][reg];
        v = v > 0.f ? v : 0.f;
        const long idx = (long)row * N + col;
        key_f[idx]  = v;
        key_bf[idx] = f2bf_rne(v);
      }
    }
  }
}

// ===== GEMM2: depth-3 test — NBUF=4, BM=128/BN=128, counted vmcnt(8) =====
// Measured axes: depth1->2 = +1.4us (R9); occupancy 8 vs 12 waves = flat
// (R17 vs R19); BN=64 hurts (R12); BM=256 neutral (R19). Depth-3 extends the
// positive direction: each tile gets 2 K-steps of flight (~680cy) vs ~500cy
// L2/HBM latency. LDS 4x16=64KB -> 2 blk/CU (measured-neutral occupancy).
// Wait ladder: steady vmcnt(8) (t+2,t+3 in flight); tail vmcnt(4), vmcnt(0).
#define G2_BM 128
#define G2_BN 128
#define NBUF 4

__global__ __launch_bounds__(256, 2)
void gemm2(const u16* __restrict__ A, const u16* __restrict__ B,
           float* __restrict__ C,
           int M, int N, int K,
           long sA_batch, long sB_batch, long sC_batch)
{
  __shared__ __align__(16) u16 sA[NBUF][G2_BM * BK];  // 4 x 8 KB
  __shared__ __align__(16) u16 sB[NBUF][G2_BN * BK];  // 4 x 8 KB
  const int tid  = threadIdx.x;
  const int wave = tid >> 6;
  const int lane = tid & 63;
  const int quad = lane >> 4;
  const int r    = lane & 15;
  const int wm   = wave >> 1;
  const int wn   = wave & 1;

  // XCD-chunked bijective swizzle: grid (8,16,8), batch bz -> XCD bz
  const int gx  = gridDim.x, gy = gridDim.y;
  const int nwg = gx * gy * (int)gridDim.z;
  const int id  = (int)blockIdx.x + gx * ((int)blockIdx.y + gy * (int)blockIdx.z);
  const int cpx = nwg >> 3;
  const int lid = (id & 7) * cpx + (id >> 3);
  const int bx  = lid % gx;
  const int tq  = lid / gx;
  const int by  = tq % gy;
  const int bz  = tq / gy;

  const int bm    = by * G2_BM;
  const int bn    = bx * G2_BN;
  const int batch = bz;

  const long ldr = (long)K * 2;
  const char* Asrc = (const char*)(A + (long)batch * sA_batch) + (long)bm * ldr;
  const char* Bsrc = (const char*)(B + (long)batch * sB_batch) + (long)bn * ldr;

  const int o0 = wave * 1024 + lane * 16;
  // 2 gload_lds/thread per 8KB tile; pre-swizzled global src chunk.
  auto stage = [&](u16* dst, const char* src, int kt) {
    #pragma unroll
    for (int rr = 0; rr < 2; rr++) {
      const int o    = rr * 4096 + o0;
      const int row  = o >> 6;
      const int jl   = (o >> 4) & 3;
      const char* g = src + (long)row * ldr + (long)kt * 2 + SWZ(row, jl) * 16;
      char* l = (char*)dst + rr * 4096 + wave * 1024;
      __builtin_amdgcn_global_load_lds((const __attribute__((address_space(1))) void*)g,
                                       (__attribute__((address_space(3))) void*)l, 16, 0, 0);
    }
  };

  f32x4 acc[4][4];
  #pragma unroll
  for (int i = 0; i < 4; i++)
    #pragma unroll
    for (int j = 0; j < 4; j++)
      acc[i][j] = f32x4{0.f, 0.f, 0.f, 0.f};

  // depth-3 prologue: tiles 0,1,2 in flight (12 loads); vmcnt(8) retires tile 0
  stage(&sA[0][0], Asrc, 0);        stage(&sB[0][0], Bsrc, 0);
  stage(&sA[1][0], Asrc, BK);       stage(&sB[1][0], Bsrc, BK);
  stage(&sA[2][0], Asrc, 2 * BK);   stage(&sB[2][0], Bsrc, 2 * BK);
  asm volatile("s_waitcnt vmcnt(8)" ::: "memory");
  __builtin_amdgcn_s_barrier();
  __builtin_amdgcn_sched_barrier(0);

  const int NT = K / BK;   // 8
  for (int t = 0; t < NT; ++t) {
    const int cur = t & 3;           // t % 4
    if (t + 3 < NT) {
      const int nb = (t + 3) & 3;
      stage(&sA[nb][0], Asrc, (t + 3) * BK);
      stage(&sB[nb][0], Bsrc, (t + 3) * BK);
    }
    bf16x8 af[4], bfr[4];
    #pragma unroll
    for (int i = 0; i < 4; i++) {
      const int row = wm * 64 + i * 16 + r;
      af[i] = *(const bf16x8*)&sA[cur][row * BK + SWZ(row, quad) * 8];
    }
    #pragma unroll
    for (int j = 0; j < 4; j++) {
      const int row = wn * 64 + j * 16 + r;
      bfr[j] = *(const bf16x8*)&sB[cur][row * BK + SWZ(row, quad) * 8];
    }
    #pragma unroll
    for (int i = 0; i < 4; i++)
      #pragma unroll
      for (int j = 0; j < 4; j++)
        acc[i][j] = __builtin_amdgcn_mfma_f32_16x16x32_bf16(af[i], bfr[j], acc[i][j], 0, 0, 0);
    if (t + 1 < NT) {
      // retire tile t+1; leave deeper tiles' loads in flight across the barrier
      if (t + 3 < NT)      asm volatile("s_waitcnt vmcnt(8)" ::: "memory");
      else if (t + 2 < NT) asm volatile("s_waitcnt vmcnt(4)" ::: "memory");
      else                 asm volatile("s_waitcnt vmcnt(0)" ::: "memory");
      __builtin_amdgcn_s_barrier();
      __builtin_amdgcn_sched_barrier(0);
    }
  }

  float* Co = C + (long)batch * sC_batch;
  #pragma unroll
  for (int i = 0; i < 4; i++) {
    #pragma unroll
    for (int j = 0; j < 4; j++) {
      #pragma unroll
      for (int reg = 0; reg < 4; reg++) {
        const int row = bm + wm * 64 + i * 16 + quad * 4 + reg;
        const int col = bn + wn * 64 + j * 16 + r;
        Co[(long)row * N + col] = acc[i][j][reg];
      }
    }
  }
}

extern "C" void kernel_launch(void* const* d_in, const int* in_sizes, int n_in,
                              void* d_out, int out_size, void* d_ws, size_t ws_size,
                              hipStream_t stream) {
  const float* x   = (const float*)d_in[0];  // (8,2048,256) fp32
  const float* mem = (const float*)d_in[1];  // (8,1024,256) fp32
  const float* W   = (const float*)d_in[2];  // (256,256)    fp32
  float* out   = (float*)d_out;
  float* key_f = out;            // (16384,256)
  float* val_f = out + NX;       // (8,2048,1024)
  u16* ws     = (u16*)d_ws;
  u16* mem_bf = ws;              // NM elems
  u16* key_bf = ws + NM;         // NX elems

  // 1) fused: GEMM1 (512 blocks) + mem conversion (1024 blocks), one dispatch
  g1_fused<<<G1_BLOCKS + (int)(NM / 2048), 256, 0, stream>>>(
      x, W, mem, key_f, key_bf, mem_bf);

  // 2) val_b = key_b @ mem_b^T: per batch M=2048, N=1024, K=256; depth-3
  dim3 g2(1024 / G2_BN, 2048 / G2_BM, 8);   // (8,16,8) = 1024 blocks
  gemm2<<<g2, 256, 0, stream>>>(key_bf, mem_bf, val_f,
                                2048, 1024, 256,
                                (long)2048 * 256, (long)1024 * 256,
                                (long)2048 * 1024);
}